// Round 14
// baseline (30.363 us; speedup 1.0000x reference)
//
#include <hip/hip_runtime.h>

typedef __attribute__((ext_vector_type(8))) short bf16x8;
typedef __attribute__((ext_vector_type(4))) float f32x4;
typedef __attribute__((ext_vector_type(4))) ushort u16x4;

#define C_DIM 256
#define S_DIM 512
#define P_DIM 128
#define K_DIM 512
#define INV_BW 20.0f
#define EPS_LOSS 1e-5f

// ws layout (float offsets) — every cell overwritten each call
#define OFF_DIAG   0          // [2][512] fp32 diag of E
#define OFF_EBF    1024       // ushort[2][512][512] = 262144 float slots
#define OFF_ETBF   263168     // ushort[2][512][512]
#define OFF_PART   525312     // float[128] per-block loss partials
#define OFF_BAR    525440     // int[1] loss ticket (re-armed by gram blk 0)

__device__ inline ushort f2bf(float f) {   // RNE float->bf16 (finite inputs)
  union { float f; uint u; } v; v.f = f;
  return (ushort)((v.u + 0x7FFF + ((v.u >> 16) & 1)) >> 16);
}
__device__ inline float bf2f(ushort u) {
  union { uint u; float f; } v; v.u = ((uint)u) << 16;
  return v.f;
}

// K1: self-staging Gram+exp, 64x32 tiles. Block = (mb: 64 m-rows, nb: 32 t-cols, b).
// Stage A(64x256)+B(32x256) fp32->bf16 LDS; per-row sumsq in-block; 4 waves,
// each: preload A-frags for its 16-row m-tile, 2 n-tiles x 8 MFMA (K=256).
// Epilogue: scale+__expf -> bf16 E + packed ET + fp32 diag.
__global__ __launch_bounds__(256) void gram_exp_kernel(
    const float* __restrict__ t2, const float* __restrict__ t1,
    ushort* __restrict__ Ebf, ushort* __restrict__ ETbf,
    float* __restrict__ diag, int* __restrict__ bar) {
  __shared__ ushort A_[64][260];
  __shared__ ushort B_[32][260];
  __shared__ float sA[64], sB[32];
  int blk = blockIdx.x, tid = threadIdx.x;
  if (blk == 0 && tid == 0) bar[0] = 0;   // re-arm loss ticket each call
  int mb = blk & 7, nb = (blk >> 3) & 15, b = blk >> 7;
  int m0 = mb * 64, c0 = nb * 32;
  {
    const float* pa = t2 + (b * C_DIM + tid) * S_DIM + m0;
    const float* pb = t1 + (b * C_DIM + tid) * S_DIM + c0;
    #pragma unroll
    for (int q = 0; q < 16; ++q) {
      float4 va = *reinterpret_cast<const float4*>(pa + q * 4);
      A_[q * 4 + 0][tid] = f2bf(va.x); A_[q * 4 + 1][tid] = f2bf(va.y);
      A_[q * 4 + 2][tid] = f2bf(va.z); A_[q * 4 + 3][tid] = f2bf(va.w);
    }
    #pragma unroll
    for (int q = 0; q < 8; ++q) {
      float4 vb = *reinterpret_cast<const float4*>(pb + q * 4);
      B_[q * 4 + 0][tid] = f2bf(vb.x); B_[q * 4 + 1][tid] = f2bf(vb.y);
      B_[q * 4 + 2][tid] = f2bf(vb.z); B_[q * 4 + 3][tid] = f2bf(vb.w);
    }
  }
  __syncthreads();
  if (tid < 96) {
    const ushort* row = (tid < 64) ? &A_[tid][0] : &B_[tid - 64][0];
    float a0 = 0.f, a1 = 0.f, a2 = 0.f, a3 = 0.f;
    #pragma unroll
    for (int k = 0; k < 64; ++k) {
      u16x4 v = *reinterpret_cast<const u16x4*>(row + k * 4);
      float x0 = bf2f(v.x), x1 = bf2f(v.y), x2 = bf2f(v.z), x3 = bf2f(v.w);
      a0 += x0 * x0; a1 += x1 * x1; a2 += x2 * x2; a3 += x3 * x3;
    }
    float sc = 1.0f / fmaxf(sqrtf((a0 + a1) + (a2 + a3)), 1e-12f);
    if (tid < 64) sA[tid] = sc; else sB[tid - 64] = sc;
  }
  __syncthreads();
  int wave = tid >> 6, lane = tid & 63;
  int lr = lane & 15, lo = lane >> 4;
  bf16x8 afr[8];                            // A-frags for m-tile = wave
  #pragma unroll
  for (int k = 0; k < 8; ++k)
    afr[k] = *reinterpret_cast<const bf16x8*>(&A_[wave * 16 + lr][lo * 8 + k * 32]);
  ushort* Eb  = Ebf  + b * (S_DIM * S_DIM);
  ushort* ETb = ETbf + b * (S_DIM * S_DIM);
  int mg0 = m0 + wave * 16;
  #pragma unroll
  for (int tn = 0; tn < 2; ++tn) {
    f32x4 acc = {0.f, 0.f, 0.f, 0.f};
    #pragma unroll
    for (int k = 0; k < 8; ++k) {
      bf16x8 bv = *reinterpret_cast<const bf16x8*>(&B_[tn * 16 + lr][lo * 8 + k * 32]);
      acc = __builtin_amdgcn_mfma_f32_16x16x32_bf16(afr[k], bv, acc, 0, 0, 0);
    }
    int cg0 = c0 + tn * 16;
    float bs = sB[tn * 16 + lr];
    float e[4]; ushort eb[4];
    #pragma unroll
    for (int r = 0; r < 4; ++r) {
      int rl = wave * 16 + lo * 4 + r;
      float ev = __expf(acc[r] * sA[rl] * bs * INV_BW);
      e[r] = ev; eb[r] = f2bf(ev);
      Eb[(m0 + rl) * S_DIM + cg0 + lr] = eb[r];
    }
    u16x4 pk = {eb[0], eb[1], eb[2], eb[3]};
    *reinterpret_cast<u16x4*>(&ETb[(cg0 + lr) * S_DIM + mg0 + lo * 4]) = pk;
    if (mg0 == cg0 && (lr >> 2) == lo) diag[b * S_DIM + mg0 + lr] = e[lr & 3];
  }
}

// K2: fused denom+loss. Block = (m: 16 patches, b, o: 64-col eighth);
// 128 blocks x 512 thr (8 waves). LDS histogram -> bf16 cnt (520-pitch) ->
// 8 wave-jobs (z x 4 col-tiles) MFMA K=512 -> D1L/D2L in LDS -> loss terms
// filtered (s>>6)==o -> partial + ticket; last of 128 reduces.
__global__ __launch_bounds__(512) void denom_loss_kernel(
    const ushort* __restrict__ Ebf, const ushort* __restrict__ ETbf,
    const int* __restrict__ idx, const float* __restrict__ diag,
    float* __restrict__ part, int* __restrict__ bar, float* __restrict__ out) {
  __shared__ int hist[16][516];
  __shared__ ushort cb[16][520];
  __shared__ float D1L[16][68], D2L[16][68];
  int blk = blockIdx.x, tid = threadIdx.x;
  int m = blk & 7, b = (blk >> 3) & 1, o = blk >> 4;
  int p0 = m * 16;
  int wave = tid >> 6, lane = tid & 63;
  int lr = lane & 15, lo = lane >> 4;
  // ---- histogram of this block's 16 idx rows ----
  {
    int p = tid >> 5, l = tid & 31;
    int* hp = &hist[p][0];
    #pragma unroll
    for (int j = 0; j < 16; ++j) hp[l * 16 + j] = 0;
    __syncthreads();
    const int* ip = idx + (p0 + p) * K_DIM + l;
    #pragma unroll
    for (int j = 0; j < 16; ++j) atomicAdd(&hp[ip[j * 32]], 1);
    __syncthreads();
    #pragma unroll
    for (int j = 0; j < 16; ++j) {
      int col = l * 16 + j;
      cb[p][col] = f2bf((float)hp[col]);
    }
  }
  __syncthreads();
  // ---- denominators: wave-job (z = wave>>2, jt = wave&3), K=512 ----
  {
    int z = wave >> 2, jt = wave & 3;
    int col0g = o * 64 + jt * 16, col0l = jt * 16;
    const ushort* Bmat = (z ? Ebf : ETbf) + b * (S_DIM * S_DIM);
    const ushort* bptr = Bmat + (col0g + lr) * S_DIM + lo * 8;
    f32x4 acc = {0.f, 0.f, 0.f, 0.f};
    #pragma unroll
    for (int k = 0; k < 16; ++k) {
      bf16x8 af = *reinterpret_cast<const bf16x8*>(&cb[lr][lo * 8 + k * 32]);
      bf16x8 bv = *reinterpret_cast<const bf16x8*>(bptr + k * 32);
      acc = __builtin_amdgcn_mfma_f32_16x16x32_bf16(af, bv, acc, 0, 0, 0);
    }
    #pragma unroll
    for (int r = 0; r < 4; ++r) {
      int p = lo * 4 + r;
      if (z) D2L[p][col0l + lr] = acc[r];
      else   D1L[p][col0l + lr] = acc[r];
    }
  }
  __syncthreads();
  // ---- loss terms with s in this 64-col eighth ----
  {
    int p = tid >> 5, l = tid & 31;
    const int* ip = idx + (p0 + p) * K_DIM + l;
    float acc = 0.f;
    #pragma unroll
    for (int j = 0; j < 16; ++j) {
      int s = ip[j * 32];
      if ((s >> 6) == o) {
        int sl = s & 63;
        float pos = diag[b * S_DIM + s];
        float d1 = D1L[p][sl];
        float d2 = D2L[p][sl];
        acc += __logf(0.5f * (pos / d1 + pos / d2) + EPS_LOSS);
      }
    }
    for (int off = 32; off; off >>= 1) acc += __shfl_down(acc, off);
    __shared__ float red[8];
    __shared__ int lastflag;
    if (lane == 0) red[wave] = acc;
    __syncthreads();
    if (tid == 0) {
      float tsum = 0.f;
      #pragma unroll
      for (int i = 0; i < 8; ++i) tsum += red[i];
      atomicExch(&part[blk], tsum);
      __threadfence();
      int old = atomicAdd(&bar[0], 1);
      lastflag = (old == 127);
    }
    __syncthreads();
    if (lastflag) {
      __threadfence();
      float v = (tid < P_DIM) ? atomicAdd(&part[tid], 0.0f) : 0.0f;
      for (int off = 32; off; off >>= 1) v += __shfl_down(v, off);
      __shared__ float red2[8];
      if (lane == 0) red2[wave] = v;
      __syncthreads();
      if (tid == 0) {
        float tsum = red2[0] + red2[1];
        out[0] = -tsum * (1.0f / (P_DIM * 2.0f * K_DIM));
      }
    }
  }
}

extern "C" void kernel_launch(void* const* d_in, const int* in_sizes, int n_in,
                              void* d_out, int out_size, void* d_ws, size_t ws_size,
                              hipStream_t stream) {
  const float* t2 = (const float*)d_in[0];
  const float* t1 = (const float*)d_in[1];
  const int* idx  = (const int*)d_in[2];
  float* ws = (float*)d_ws;
  float*  diag   = ws + OFF_DIAG;
  ushort* Ebf    = (ushort*)(ws + OFF_EBF);
  ushort* ETbf   = (ushort*)(ws + OFF_ETBF);
  float*  part   = ws + OFF_PART;
  int*    bar    = (int*)(ws + OFF_BAR);

  gram_exp_kernel<<<256, 256, 0, stream>>>(t2, t1, Ebf, ETbf, diag, bar);
  denom_loss_kernel<<<128, 512, 0, stream>>>(Ebf, ETbf, idx, diag, part, bar,
                                             (float*)d_out);
}

// Round 15
// 29.228 us; speedup vs baseline: 1.0388x; 1.0388x over previous
//
#include <hip/hip_runtime.h>

typedef __attribute__((ext_vector_type(8))) short bf16x8;
typedef __attribute__((ext_vector_type(4))) float f32x4;
typedef __attribute__((ext_vector_type(4))) ushort u16x4;

#define C_DIM 256
#define S_DIM 512
#define P_DIM 128
#define K_DIM 512
#define INV_BW 20.0f
#define EPS_LOSS 1e-5f

// ws layout (float offsets) — every cell overwritten each call
#define OFF_DIAG   0          // [2][512] fp32 diag of E
#define OFF_EBF    1024       // ushort[2][512][512] = 262144 float slots
#define OFF_ETBF   263168     // ushort[2][512][512]
#define OFF_PART   525312     // float[64] per-block loss partials
#define OFF_BAR    525376     // int[1] loss ticket (re-armed by gram blk 0)

__device__ inline ushort f2bf(float f) {   // RNE float->bf16 (finite inputs)
  union { float f; uint u; } v; v.f = f;
  return (ushort)((v.u + 0x7FFF + ((v.u >> 16) & 1)) >> 16);
}
__device__ inline float bf2f(ushort u) {
  union { uint u; float f; } v; v.u = ((uint)u) << 16;
  return v.f;
}

// K1: self-staging Gram+exp. Block = 32x32 E-tile region for batch b.
__global__ __launch_bounds__(256) void gram_exp_kernel(
    const float* __restrict__ t2, const float* __restrict__ t1,
    ushort* __restrict__ Ebf, ushort* __restrict__ ETbf,
    float* __restrict__ diag, int* __restrict__ bar) {
  __shared__ ushort A_[32][264];   // [s-local][c] bf16 of t2 panel
  __shared__ ushort B_[32][264];   // [t-local][c] bf16 of t1 panel
  __shared__ float sA[32], sB[32];
  int blk = blockIdx.x, tid = threadIdx.x;
  if (blk == 0 && tid == 0) bar[0] = 0;   // re-arm loss ticket each call
  int mb = blk & 15, nb = (blk >> 4) & 15, b = blk >> 8;
  int m0 = mb * 32, c0 = nb * 32;
  {
    const float* pa = t2 + (b * C_DIM + tid) * S_DIM + m0;
    const float* pb = t1 + (b * C_DIM + tid) * S_DIM + c0;
    #pragma unroll
    for (int q = 0; q < 8; ++q) {
      float4 va = *reinterpret_cast<const float4*>(pa + q * 4);
      float4 vb = *reinterpret_cast<const float4*>(pb + q * 4);
      A_[q * 4 + 0][tid] = f2bf(va.x); A_[q * 4 + 1][tid] = f2bf(va.y);
      A_[q * 4 + 2][tid] = f2bf(va.z); A_[q * 4 + 3][tid] = f2bf(va.w);
      B_[q * 4 + 0][tid] = f2bf(vb.x); B_[q * 4 + 1][tid] = f2bf(vb.y);
      B_[q * 4 + 2][tid] = f2bf(vb.z); B_[q * 4 + 3][tid] = f2bf(vb.w);
    }
  }
  __syncthreads();
  if (tid < 64) {
    const ushort* row = (tid < 32) ? &A_[tid][0] : &B_[tid - 32][0];
    float a0 = 0.f, a1 = 0.f, a2 = 0.f, a3 = 0.f;
    #pragma unroll
    for (int k = 0; k < 64; ++k) {
      u16x4 v = *reinterpret_cast<const u16x4*>(row + k * 4);
      float x0 = bf2f(v.x), x1 = bf2f(v.y), x2 = bf2f(v.z), x3 = bf2f(v.w);
      a0 += x0 * x0; a1 += x1 * x1; a2 += x2 * x2; a3 += x3 * x3;
    }
    float sc = 1.0f / fmaxf(sqrtf((a0 + a1) + (a2 + a3)), 1e-12f);
    if (tid < 32) sA[tid] = sc; else sB[tid - 32] = sc;
  }
  __syncthreads();
  int wave = tid >> 6, lane = tid & 63;
  int tm = wave & 1, tn = wave >> 1;
  int lr = lane & 15, lo = lane >> 4;
  f32x4 acc = {0.f, 0.f, 0.f, 0.f};
  #pragma unroll
  for (int k = 0; k < 8; ++k) {
    bf16x8 af = *reinterpret_cast<const bf16x8*>(&A_[tm * 16 + lr][lo * 8 + k * 32]);
    bf16x8 bv = *reinterpret_cast<const bf16x8*>(&B_[tn * 16 + lr][lo * 8 + k * 32]);
    acc = __builtin_amdgcn_mfma_f32_16x16x32_bf16(af, bv, acc, 0, 0, 0);
  }
  int mg0 = m0 + tm * 16, cg0 = c0 + tn * 16;
  float bs = sB[tn * 16 + lr];
  ushort* Eb  = Ebf  + b * (S_DIM * S_DIM);
  ushort* ETb = ETbf + b * (S_DIM * S_DIM);
  float e[4]; ushort eb[4];
  #pragma unroll
  for (int r = 0; r < 4; ++r) {
    int rl = tm * 16 + lo * 4 + r;
    float ev = __expf(acc[r] * sA[rl] * bs * INV_BW);
    e[r] = ev; eb[r] = f2bf(ev);
    Eb[(m0 + rl) * S_DIM + cg0 + lr] = eb[r];
  }
  u16x4 pk = {eb[0], eb[1], eb[2], eb[3]};
  *reinterpret_cast<u16x4*>(&ETb[(cg0 + lr) * S_DIM + mg0 + lo * 4]) = pk;
  if (mg0 == cg0 && (lr >> 2) == lo) diag[b * S_DIM + mg0 + lr] = e[lr & 3];
}

// K2: fused denom+loss. Block = (m: 16 patches, b, q: 128-col quarter);
// 64 blocks x 1024 thr (16 waves). LDS histogram -> bf16 cnt (520-pitch) ->
// 16 wave-jobs MFMA K=512 (B from L2 quarter of Ebf/ETbf) -> D1L/D2L in LDS ->
// loss terms filtered s-in-quarter -> partial + ticket; last of 64 reduces.
__global__ __launch_bounds__(1024) void denom_loss_kernel(
    const ushort* __restrict__ Ebf, const ushort* __restrict__ ETbf,
    const int* __restrict__ idx, const float* __restrict__ diag,
    float* __restrict__ part, int* __restrict__ bar, float* __restrict__ out) {
  __shared__ int hist[16][516];
  __shared__ ushort cb[16][520];
  __shared__ float D1L[16][132], D2L[16][132];
  int blk = blockIdx.x, tid = threadIdx.x;
  int m = blk & 7, b = (blk >> 3) & 1, q = blk >> 4;
  int p0 = m * 16;
  int wave = tid >> 6, lane = tid & 63;
  int lr = lane & 15, lo = lane >> 4;
  // ---- histogram of this block's 16 idx rows ----
  {
    int p = tid >> 6, l = tid & 63;
    int* hp = &hist[p][0];
    #pragma unroll
    for (int j = 0; j < 8; ++j) hp[l * 8 + j] = 0;
    __syncthreads();
    const int* ip = idx + (p0 + p) * K_DIM + l;
    #pragma unroll
    for (int j = 0; j < 8; ++j) atomicAdd(&hp[ip[j * 64]], 1);
    __syncthreads();
    #pragma unroll
    for (int j = 0; j < 8; ++j) {
      int col = l * 8 + j;
      cb[p][col] = f2bf((float)hp[col]);
    }
  }
  __syncthreads();
  // ---- denominators: wave-job (z = wave>>3, jt = wave&7), K=512 ----
  {
    int z = wave >> 3, jt = wave & 7;
    int col0g = q * 128 + jt * 16, col0l = jt * 16;
    const ushort* Bmat = (z ? Ebf : ETbf) + b * (S_DIM * S_DIM);
    const ushort* bptr = Bmat + (col0g + lr) * S_DIM + lo * 8;
    f32x4 acc = {0.f, 0.f, 0.f, 0.f};
    #pragma unroll
    for (int k = 0; k < 16; ++k) {
      bf16x8 af = *reinterpret_cast<const bf16x8*>(&cb[lr][lo * 8 + k * 32]);
      bf16x8 bv = *reinterpret_cast<const bf16x8*>(bptr + k * 32);
      acc = __builtin_amdgcn_mfma_f32_16x16x32_bf16(af, bv, acc, 0, 0, 0);
    }
    #pragma unroll
    for (int r = 0; r < 4; ++r) {
      int p = lo * 4 + r;
      if (z) D2L[p][col0l + lr] = acc[r];
      else   D1L[p][col0l + lr] = acc[r];
    }
  }
  __syncthreads();
  // ---- loss terms with s in this quarter ----
  {
    int p = tid >> 6, l = tid & 63;
    const int* ip = idx + (p0 + p) * K_DIM + l;
    float acc = 0.f;
    #pragma unroll
    for (int j = 0; j < 8; ++j) {
      int s = ip[j * 64];
      if ((s >> 7) == q) {
        int sl = s & 127;
        float pos = diag[b * S_DIM + s];
        float d1 = D1L[p][sl];
        float d2 = D2L[p][sl];
        acc += __logf(0.5f * (pos / d1 + pos / d2) + EPS_LOSS);
      }
    }
    for (int o = 32; o; o >>= 1) acc += __shfl_down(acc, o);
    __shared__ float red[16];
    __shared__ int lastflag;
    if (lane == 0) red[wave] = acc;
    __syncthreads();
    if (tid == 0) {
      float tsum = 0.f;
      #pragma unroll
      for (int i = 0; i < 16; ++i) tsum += red[i];
      atomicExch(&part[blk], tsum);
      __threadfence();
      int old = atomicAdd(&bar[0], 1);
      lastflag = (old == 63);
    }
    __syncthreads();
    if (lastflag && tid < 64) {
      __threadfence();
      float v = atomicAdd(&part[tid], 0.0f);   // coherent read
      for (int o = 32; o; o >>= 1) v += __shfl_down(v, o);
      if (tid == 0) out[0] = -v * (1.0f / (P_DIM * 2.0f * K_DIM));
    }
  }
}

extern "C" void kernel_launch(void* const* d_in, const int* in_sizes, int n_in,
                              void* d_out, int out_size, void* d_ws, size_t ws_size,
                              hipStream_t stream) {
  const float* t2 = (const float*)d_in[0];
  const float* t1 = (const float*)d_in[1];
  const int* idx  = (const int*)d_in[2];
  float* ws = (float*)d_ws;
  float*  diag   = ws + OFF_DIAG;
  ushort* Ebf    = (ushort*)(ws + OFF_EBF);
  ushort* ETbf   = (ushort*)(ws + OFF_ETBF);
  float*  part   = ws + OFF_PART;
  int*    bar    = (int*)(ws + OFF_BAR);

  gram_exp_kernel<<<512, 256, 0, stream>>>(t2, t1, Ebf, ETbf, diag, bar);
  denom_loss_kernel<<<64, 1024, 0, stream>>>(Ebf, ETbf, idx, diag, part, bar,
                                             (float*)d_out);
}